// Round 8
// baseline (163.590 us; speedup 1.0000x reference)
//
#include <hip/hip_runtime.h>

#define E 288
#define NSEQ 2048
#define BATCH 4
#define NH 8
#define HD 36
#define BH (BATCH * NH)      // 32
#define ROWS (BATCH * NSEQ)  // 8192
#define BHN (BH * NSEQ)      // 65536

typedef _Float16 half8_t __attribute__((ext_vector_type(8)));
typedef _Float16 half4_t __attribute__((ext_vector_type(4)));
typedef _Float16 half2_t __attribute__((ext_vector_type(2)));
typedef float f32x4 __attribute__((ext_vector_type(4)));
typedef int i32x4 __attribute__((ext_vector_type(4)));

// --- swizzle for 64-half rows (attn K/V tiles) ----------------------------
__device__ __forceinline__ int sw64(int row, int col) {
  return (row << 6) + ((((col >> 3) ^ row) & 7) << 3) + (col & 7);
}

// --- packed-tile swizzle for T x 32-half tiles (proj A/W tiles) -----------
__device__ __forceinline__ int toff(int r, int k) {
  const int rp = r >> 1;
  const int g = (((r & 1) << 2) + (k >> 3)) ^ (rp & 7);
  return (rp << 6) + ((g & 7) << 3) + (k & 7);
}

// async global->LDS, 16 B per lane; LDS dest wave-uniform, lanes +16 B
__device__ __forceinline__ void gld16(const _Float16* g, _Float16* l) {
  __builtin_amdgcn_global_load_lds(
      (const __attribute__((address_space(1))) void*)g,
      (__attribute__((address_space(3))) void*)l, 16, 0, 0);
}

__device__ __forceinline__ float fexp2(float x) {
  return __builtin_amdgcn_exp2f(x);
}

// pack two f32 -> one u32 of 2x f16 (RNE, same rounding as scalar casts)
__device__ __forceinline__ unsigned pack_h2(float a, float b) {
  union { half2_t h; unsigned u; } cv;
  cv.h[0] = (_Float16)a;
  cv.h[1] = (_Float16)b;
  return cv.u;
}

// in-place cross-lane swaps (gfx950): both operands exchanged
__device__ __forceinline__ void plswap16(unsigned& a, unsigned& b) {
  asm("v_permlane16_swap_b32 %0, %1" : "+v"(a), "+v"(b));
}
__device__ __forceinline__ void plswap32(unsigned& a, unsigned& b) {
  asm("v_permlane32_swap_b32 %0, %1" : "+v"(a), "+v"(b));
}

// ===========================================================================
// prep: (a) W fp32 [k][n] -> fp16 pre-swizzled 96x32 tile blocks (transposed)
//       (b) zero q16 pad region d in [32,64) only (proj writes d<36 after)
//       (c) ones into vblk row d=36 of every tile (softmax denominator free)
//       (d) x (q/k/v inputs) fp32 -> fp16 pre-swizzled 128x32 A-tiles so
//           proj_qkv can stage A via global_load_lds (no VALU convert path)
// ===========================================================================
#define WBLK 1296   // 4*288*288 / 256
#define QZBLK 1024  // BHN rows * 4 i32x4 (upper 32 halves) / 256
#define VOBLK 256   // BH*32*64 / 256
#define XBLK 3456   // 3*8192*36 / 256

__global__ __launch_bounds__(256) void prep_kernel(
    const float* __restrict__ Wq, const float* __restrict__ Wk,
    const float* __restrict__ Wv, const float* __restrict__ Wo,
    const float* __restrict__ xq, const float* __restrict__ xk,
    const float* __restrict__ xv, _Float16* __restrict__ wblk,
    _Float16* __restrict__ q16, _Float16* __restrict__ vblk,
    _Float16* __restrict__ xblk) {
  const int bid = blockIdx.x;
  const int tid = threadIdx.x;
  if (bid < WBLK) {
    const int j = bid * 256 + tid;  // (m, k, n)
    const int m = j / (E * E);
    const int rem = j - m * (E * E);
    const int k = rem / E, n = rem - k * E;
    const float* W = (m == 0) ? Wq : (m == 1) ? Wk : (m == 2) ? Wv : Wo;
    wblk[(size_t)((m * 3 + n / 96) * 9 + (k >> 5)) * 3072 +
         toff(n % 96, k & 31)] = (_Float16)W[(size_t)k * E + n];
  } else if (bid < WBLK + QZBLK) {
    const int j = (bid - WBLK) * 256 + tid;  // (row, sub)
    const int row = j >> 2, sub = j & 3;
    ((i32x4*)q16)[(size_t)row * 8 + 4 + sub] = (i32x4){0, 0, 0, 0};
  } else if (bid < WBLK + QZBLK + VOBLK) {
    const int j = (bid - WBLK - QZBLK) * 256 + tid;  // (bh, kt, c)
    const int bh = j >> 11;
    const int rem = j & 2047;
    const int kt = rem >> 6, c = rem & 63;
    vblk[((size_t)bh * 32 + kt) * 3072 + sw64(36, c)] = (_Float16)1.0f;
  } else {
    const int j = (bid - WBLK - QZBLK - VOBLK) * 256 + tid;  // (m, row, c8)
    const int m = j / (ROWS * 36);
    const int rem = j - m * (ROWS * 36);
    const int row = rem / 36, c8 = rem - row * 36;
    const int col = c8 * 8;
    const float* x = (m == 0) ? xq : (m == 1) ? xk : xv;
    const float4 a = *(const float4*)&x[(size_t)row * E + col];
    const float4 b = *(const float4*)&x[(size_t)row * E + col + 4];
    half8_t h = {(_Float16)a.x, (_Float16)a.y, (_Float16)a.z, (_Float16)a.w,
                 (_Float16)b.x, (_Float16)b.y, (_Float16)b.z, (_Float16)b.w};
    *(half8_t*)&xblk[(size_t)((m * 64 + (row >> 7)) * 9 + (col >> 5)) * 4096 +
                     toff(row & 127, col & 31)] = h;
  }
}

// ===========================================================================
// QKV projection: BOTH operands staged via gld16 from pre-swizzled tiles
// (xblk A-tiles + wblk W-tiles). Double-buffered, ONE barrier per K-chunk.
// PM=128 x PN=96, 9 chunks of K=32. Epilogue unchanged:
// mode 0 -> q16 [bh][n][64]; mode 1 -> kblk sw64(c,d); mode 2 -> vblk
// sw64(d,pi(c)).
// ===========================================================================
#define PM 128
#define PN 96

struct QKVOut {
  const float* bias[3];
  _Float16* out[3];
};

__global__ __launch_bounds__(256, 4) void proj_qkv_kernel(
    QKVOut A, const _Float16* __restrict__ wblk,
    const _Float16* __restrict__ xblk) {
  __shared__ __align__(16) _Float16 abuf[2][4096];
  __shared__ __align__(16) _Float16 wbuf[2][3072];

  const int tid = threadIdx.x;
  const int lane = tid & 63, w = tid >> 6;
  const int quad = lane >> 4, l15 = lane & 15;
  const int mode = blockIdx.z;
  const int RB = blockIdx.x, CT = blockIdx.y;
  const _Float16* __restrict__ wb = wblk + (size_t)(mode * 3 + CT) * 9 * 3072;
  const _Float16* __restrict__ xb = xblk + (size_t)(mode * 64 + RB) * 9 * 4096;
  const int row0 = RB * PM;

  auto stageA = [&](int C, _Float16* dst) {
#pragma unroll
    for (int seg = w; seg < 8; seg += 4)
      gld16(xb + C * 4096 + seg * 512 + lane * 8, dst + seg * 512);
  };
  auto stageW = [&](int C, _Float16* dst) {
    for (int seg = w; seg < 6; seg += 4)
      gld16(wb + C * 3072 + seg * 512 + lane * 8, dst + seg * 512);
  };

  f32x4 acc[2][6];
#pragma unroll
  for (int t = 0; t < 2; ++t)
#pragma unroll
    for (int nt = 0; nt < 6; ++nt) acc[t][nt] = (f32x4){0.f, 0.f, 0.f, 0.f};

  stageA(0, abuf[0]);
  stageW(0, wbuf[0]);

  for (int C = 0; C < 9; ++C) {
    const int cur = C & 1;
    __syncthreads();  // drains abuf[cur]/wbuf[cur] gld16
    if (C + 1 < 9) {
      stageW(C + 1, wbuf[cur ^ 1]);
      stageA(C + 1, abuf[cur ^ 1]);
    }
    half8_t ah[2];
#pragma unroll
    for (int t = 0; t < 2; ++t)
      ah[t] = *(const half8_t*)&abuf[cur][toff(w * 32 + t * 16 + l15, quad * 8)];
#pragma unroll
    for (int nt = 0; nt < 6; ++nt) {
      const half8_t bf = *(const half8_t*)&wbuf[cur][toff(nt * 16 + l15, quad * 8)];
#pragma unroll
      for (int t = 0; t < 2; ++t)
        acc[t][nt] = __builtin_amdgcn_mfma_f32_16x16x32_f16(ah[t], bf, acc[t][nt], 0, 0, 0);
    }
  }

  const float* __restrict__ bias = A.bias[mode];
  _Float16* __restrict__ outp = A.out[mode];
  const float scale = (mode == 0) ? 0.24044917348149868f : 1.0f;
  const int col0 = CT * PN;
#pragma unroll
  for (int nt = 0; nt < 6; ++nt) {
    const int col = col0 + nt * 16 + l15;
    const int h = col / 36, d = col - h * 36;
    const float bc = bias[col];
#pragma unroll
    for (int t = 0; t < 2; ++t) {
#pragma unroll
      for (int r = 0; r < 4; ++r) {
        const int row = row0 + w * 32 + t * 16 + quad * 4 + r;
        const int b = row >> 11, n = row & (NSEQ - 1);
        const int bh = b * NH + h;
        const _Float16 val = (_Float16)((acc[t][nt][r] + bc) * scale);
        if (mode == 0) {
          outp[((size_t)bh * NSEQ + n) * 64 + d] = val;
        } else {
          const int kt = n >> 6, c = n & 63;
          if (mode == 1) {
            outp[((size_t)bh * 32 + kt) * 4096 + sw64(c, d)] = val;
          } else {
            const int pc = ((c & 15) << 2) | (c >> 4);
            outp[((size_t)bh * 32 + kt) * 3072 + sw64(d, pc)] = val;
          }
        }
      }
    }
  }
}

// ===========================================================================
// fp16 MFMA flash attention (R4 core, best measured). Epilogue writes pacc16
// row-major [chunk][row 8192][E 288] + psum_r[chunk][row][h] for fused
// combine in proj_o.
// ===========================================================================
#define QB 128
#define KT 64
#define SPLIT 2
#define NIT (32 / SPLIT)  // K-tiles per block

__device__ __forceinline__ void stage_tile(const _Float16* kg, const _Float16* vg,
                                           _Float16* kb, _Float16* vb, int w,
                                           int lane) {
#pragma unroll
  for (int seg = w; seg < 8; seg += 4)
    gld16(kg + seg * 512 + lane * 8, kb + seg * 512);
  for (int seg = w; seg < 6; seg += 4)
    gld16(vg + seg * 512 + lane * 8, vb + seg * 512);
}

__global__ __launch_bounds__(256, 4) void attn_kernel(
    const _Float16* __restrict__ q16, const _Float16* __restrict__ kblk,
    const _Float16* __restrict__ vblk, _Float16* __restrict__ pacc16,
    float* __restrict__ psum_r) {
  __shared__ __align__(16) _Float16 kbuf[2][KT * 64];  // 16 KB
  __shared__ __align__(16) _Float16 vbuf[2][48 * 64];  // 12 KB

  const int tid = threadIdx.x;
  const int lane = tid & 63;
  const int w = tid >> 6;
  const int quad = lane >> 4;
  const int l15 = lane & 15;

  const int id = blockIdx.x;
  const int xcd = id & 7;
  const int qb = (id >> 3) & 15;
  const int g = id >> 7;
  const int bhc = g * 8 + xcd;  // [0, BH*SPLIT)
  const int bh = bhc >> 1;
  const int chunk = bhc & 1;
  const int q0 = qb * QB;

  const _Float16* qbase = q16 + ((size_t)bh * NSEQ + q0 + w * 32) * 64;
  half8_t qf[2][2];
#pragma unroll
  for (int t = 0; t < 2; ++t)
#pragma unroll
    for (int kc = 0; kc < 2; ++kc)
      qf[t][kc] = *(const half8_t*)&qbase[(t * 16 + l15) * 64 + kc * 32 + quad * 8];

  f32x4 oacc[2][3];
#pragma unroll
  for (int t = 0; t < 2; ++t)
#pragma unroll
    for (int nt = 0; nt < 3; ++nt) oacc[t][nt] = (f32x4){0.f, 0.f, 0.f, 0.f};

  const f32x4 zf = (f32x4){0.f, 0.f, 0.f, 0.f};

  const int t0 = chunk * NIT;
  const _Float16* kbase = kblk + ((size_t)bh * 32 + t0) * 4096;
  const _Float16* vbase = vblk + ((size_t)bh * 32 + t0) * 3072;

  stage_tile(kbase, vbase, kbuf[0], vbuf[0], w, lane);

  for (int it = 0; it < NIT; ++it) {
    const int cur = it & 1;
    __syncthreads();
    if (it + 1 < NIT)
      stage_tile(kbase + (it + 1) * 4096, vbase + (it + 1) * 3072,
                 kbuf[cur ^ 1], vbuf[cur ^ 1], w, lane);

    // hoist V fragments (shared across both stripes; row 36 = ones)
    half8_t vf[2][3];
#pragma unroll
    for (int kc = 0; kc < 2; ++kc)
#pragma unroll
      for (int nt = 0; nt < 3; ++nt)
        vf[kc][nt] = *(const half8_t*)&vbuf[cur][sw64(nt * 16 + l15, kc * 32 + quad * 8)];

    // ---- QK^T (swapped: D = K.Q^T, lane holds q-row l15) + exp + pack ----
    unsigned pk[2][4][2];
#pragma unroll
    for (int a = 0; a < 2; ++a) {  // s-pair (2a, 2a+1)
      f32x4 sc[2][2];              // [stripe][s within pair]
      __builtin_amdgcn_s_setprio(1);
#pragma unroll
      for (int sp = 0; sp < 2; ++sp) {
        const int s = a * 2 + sp;
        const half8_t kf0 = *(const half8_t*)&kbuf[cur][sw64(s * 16 + l15, quad * 8)];
        const half8_t kf1 = *(const half8_t*)&kbuf[cur][sw64(s * 16 + l15, 32 + quad * 8)];
#pragma unroll
        for (int t = 0; t < 2; ++t) {
          f32x4 c0 = __builtin_amdgcn_mfma_f32_16x16x32_f16(
              kf0, qf[t][0], zf, 0, 0, 0);
          sc[t][sp] = __builtin_amdgcn_mfma_f32_16x16x32_f16(
              kf1, qf[t][1], c0, 0, 0, 0);
        }
      }
      __builtin_amdgcn_s_setprio(0);
#pragma unroll
      for (int t = 0; t < 2; ++t)
#pragma unroll
        for (int r = 0; r < 4; ++r) {
          const float p0 = fexp2(sc[t][0][r]);
          const float p1 = fexp2(sc[t][1][r]);
          pk[t][r][a] = pack_h2(p0, p1);
        }
    }

    // ---- in-register transpose: pk -> PV A-fragments (both kc at once) ----
    half8_t pa[2][2];
#pragma unroll
    for (int t = 0; t < 2; ++t) {
      union { unsigned u[4]; half8_t h; } f0, f1;
#pragma unroll
      for (int v = 0; v < 4; ++v) {
        unsigned x = pk[t][v >> 1][v & 1];
        unsigned y = pk[t][(v >> 1) + 2][v & 1];
        plswap16(x, y);
        plswap32(x, y);
        f0.u[v] = x;
        f1.u[v] = y;
      }
      pa[t][0] = f0.h;
      pa[t][1] = f1.h;
    }

    // ---- PV: V fragments read once, shared across both stripes ----
    __builtin_amdgcn_s_setprio(1);
#pragma unroll
    for (int kc = 0; kc < 2; ++kc)
#pragma unroll
      for (int nt = 0; nt < 3; ++nt) {
#pragma unroll
        for (int t = 0; t < 2; ++t)
          oacc[t][nt] = __builtin_amdgcn_mfma_f32_16x16x32_f16(pa[t][kc], vf[kc][nt], oacc[t][nt], 0, 0, 0);
      }
    __builtin_amdgcn_s_setprio(0);
  }

  const int b = bh >> 3, h = bh & 7;
#pragma unroll
  for (int t = 0; t < 2; ++t) {
#pragma unroll
    for (int r = 0; r < 4; ++r) {
      const int n = q0 + w * 32 + t * 16 + quad * 4 + r;
      const size_t rowg = (size_t)b * NSEQ + n;
      const size_t base = ((size_t)chunk * ROWS + rowg) * E + h * 36;
      // col 36 of oacc (nt=2, l15==4) = sum over this chunk's kv of P (f16)
      if (l15 == 4) psum_r[((size_t)chunk * ROWS + rowg) * 8 + h] = oacc[t][2][r];
#pragma unroll
      for (int nt = 0; nt < 3; ++nt) {
        const int col = nt * 16 + l15;
        if (col < HD) pacc16[base + col] = (_Float16)oacc[t][nt][r];
      }
    }
  }
}

// ===========================================================================
// O projection with FUSED split-K combine (unchanged from R7).
// PM=64 x PN=48 -> grid (128, 6) = 768 blocks = 3/CU. fp32 out.
// ===========================================================================
__global__ __launch_bounds__(256, 4) void proj_o_kernel(
    const _Float16* __restrict__ pacc16, const float* __restrict__ psum_r,
    const _Float16* __restrict__ wblk_o, const float* __restrict__ bias,
    float* __restrict__ out) {
  __shared__ __align__(16) _Float16 hbuf[2][2048];  // 8 KB
  __shared__ __align__(16) _Float16 lbuf[2][2048];  // 8 KB
  __shared__ __align__(16) _Float16 wbuf[2][1536];  // 6 KB
  __shared__ float invt[512];                       // [row 64][h 8], 2 KB

  const int tid = threadIdx.x;
  const int lane = tid & 63, w = tid >> 6;
  const int quad = lane >> 4, l15 = lane & 15;
  const int RB = blockIdx.x, CT = blockIdx.y;
  const int row0 = RB * 64;
  // 48-col half-panel of the pre-swizzled 96x32 W tiles:
  // toff(r+48,k) == toff(r,k)+1536, so half-panels are contiguous.
  const _Float16* __restrict__ wb =
      wblk_o + (size_t)(CT >> 1) * 9 * 3072 + (CT & 1) * 1536;

  // ---- build inv table: inv[r][h] = 1/(psum0 + psum1) ----
#pragma unroll
  for (int u = 0; u < 2; ++u) {
    const int idx = tid + u * 256;  // r*8 + h
    const int r = idx >> 3, hh = idx & 7;
    const float s = psum_r[(size_t)(row0 + r) * 8 + hh] +
                    psum_r[((size_t)ROWS + row0 + r) * 8 + hh];
    invt[idx] = 1.0f / s;
  }

  // ---- A prefetch (thread -> row=tid>>2, 8 cols at (tid&3)*8) ----
  const int arow = tid >> 2;
  const int acol8 = (tid & 3) * 8;
  half8_t ap0, ap1;
  auto loadA = [&](int C) {
    const size_t off = (size_t)(row0 + arow) * E + C * 32 + acol8;
    ap0 = *(const half8_t*)&pacc16[off];
    ap1 = *(const half8_t*)&pacc16[(size_t)ROWS * E + off];
  };
  auto writeA = [&](int C, _Float16* hd, _Float16* ld) {
    const int colb = C * 32 + acol8;
    const int h0 = colb / 36;
    const int h1 = (colb + 7) / 36;
    const float i0 = invt[(arow << 3) + h0];
    const float i1 = invt[(arow << 3) + h1];
    const int split = h1 * 36 - colb;  // j < split -> h0 (h0==h1 -> split<=0 -> all i1)
    half8_t hv, lv;
#pragma unroll
    for (int j = 0; j < 8; ++j) {
      const float inv = (j < split) ? i0 : i1;
      const float a = (float)ap0[j] + (float)ap1[j];
      const float val = a * inv;
      const _Float16 hi = (_Float16)val;
      hv[j] = hi;
      lv[j] = (_Float16)(val - (float)hi);
    }
    *(half8_t*)&hd[toff(arow, acol8)] = hv;
    *(half8_t*)&ld[toff(arow, acol8)] = lv;
  };

  f32x4 acc[3];
#pragma unroll
  for (int nt = 0; nt < 3; ++nt) acc[nt] = (f32x4){0.f, 0.f, 0.f, 0.f};

  loadA(0);
  __syncthreads();  // invt ready before writeA(0) reads it
  writeA(0, hbuf[0], lbuf[0]);
  for (int seg = w; seg < 3; seg += 4)
    gld16(wb + seg * 512 + lane * 8, wbuf[0] + seg * 512);
  loadA(1);

  for (int C = 0; C < 9; ++C) {
    const int cur = C & 1;
    __syncthreads();  // drains wbuf gld16 + hbuf/lbuf ds_writes for chunk C
    if (C + 1 < 9) {
      for (int seg = w; seg < 3; seg += 4)
        gld16(wb + (C + 1) * 3072 + seg * 512 + lane * 8,
              wbuf[cur ^ 1] + seg * 512);
      writeA(C + 1, hbuf[cur ^ 1], lbuf[cur ^ 1]);
      if (C + 2 < 9) loadA(C + 2);
    }
    const half8_t ah = *(const half8_t*)&hbuf[cur][toff(w * 16 + l15, quad * 8)];
    const half8_t al = *(const half8_t*)&lbuf[cur][toff(w * 16 + l15, quad * 8)];
#pragma unroll
    for (int nt = 0; nt < 3; ++nt) {
      const half8_t bf = *(const half8_t*)&wbuf[cur][toff(nt * 16 + l15, quad * 8)];
      acc[nt] = __builtin_amdgcn_mfma_f32_16x16x32_f16(ah, bf, acc[nt], 0, 0, 0);
      acc[nt] = __builtin_amdgcn_mfma_f32_16x16x32_f16(al, bf, acc[nt], 0, 0, 0);
    }
  }

#pragma unroll
  for (int nt = 0; nt < 3; ++nt) {
    const int col = CT * 48 + nt * 16 + l15;
    const float bc = bias[col];
#pragma unroll
    for (int r = 0; r < 4; ++r) {
      const int row = row0 + w * 16 + quad * 4 + r;
      out[(size_t)row * E + col] = acc[nt][r] + bc;
    }
  }
}

// ===========================================================================
extern "C" void kernel_launch(void* const* d_in, const int* in_sizes, int n_in,
                              void* d_out, int out_size, void* d_ws,
                              size_t ws_size, hipStream_t stream) {
  const float* query = (const float*)d_in[0];
  const float* key_ = (const float*)d_in[1];
  const float* value = (const float*)d_in[2];
  const float* Wq = (const float*)d_in[3];
  const float* bq = (const float*)d_in[4];
  const float* Wk = (const float*)d_in[5];
  const float* bk = (const float*)d_in[6];
  const float* Wv = (const float*)d_in[7];
  const float* bv = (const float*)d_in[8];
  const float* Wo = (const float*)d_in[9];
  const float* bo = (const float*)d_in[10];
  float* out = (float*)d_out;

  // workspace layout
  _Float16* q16 = (_Float16*)d_ws;                    // BH*NSEQ*64
  _Float16* kblk = q16 + (size_t)BH * NSEQ * 64;      // BH*32*4096
  _Float16* vblk = kblk + (size_t)BH * 32 * 4096;     // BH*32*3072
  _Float16* wblk = vblk + (size_t)BH * 32 * 3072;     // 4*3*9*3072
  _Float16* xblk = wblk + (size_t)4 * 3 * 9 * 3072;   // 3*64*9*4096
  _Float16* pacc16 = xblk + (size_t)3 * 64 * 9 * 4096;  // SPLIT*ROWS*E
  float* psum_r = (float*)(pacc16 + (size_t)SPLIT * ROWS * E);  // SPLIT*ROWS*8

  prep_kernel<<<WBLK + QZBLK + VOBLK + XBLK, 256, 0, stream>>>(
      Wq, Wk, Wv, Wo, query, key_, value, wblk, q16, vblk, xblk);

  QKVOut qa;
  qa.bias[0] = bq; qa.bias[1] = bk; qa.bias[2] = bv;
  qa.out[0] = q16; qa.out[1] = kblk; qa.out[2] = vblk;
  proj_qkv_kernel<<<dim3(ROWS / PM, E / PN, 3), 256, 0, stream>>>(qa, wblk,
                                                                  xblk);

  attn_kernel<<<dim3((NSEQ / QB) * BH * SPLIT), 256, 0, stream>>>(
      q16, kblk, vblk, pacc16, psum_r);

  proj_o_kernel<<<dim3(ROWS / 64, E / 48), 256, 0, stream>>>(
      pacc16, psum_r, wblk + (size_t)3 * 3 * 9 * 3072, bo, out);
}

// Round 9
// 156.096 us; speedup vs baseline: 1.0480x; 1.0480x over previous
//
#include <hip/hip_runtime.h>

#define E 288
#define NSEQ 2048
#define BATCH 4
#define NH 8
#define HD 36
#define BH (BATCH * NH)      // 32
#define ROWS (BATCH * NSEQ)  // 8192
#define BHN (BH * NSEQ)      // 65536

typedef _Float16 half8_t __attribute__((ext_vector_type(8)));
typedef _Float16 half4_t __attribute__((ext_vector_type(4)));
typedef _Float16 half2_t __attribute__((ext_vector_type(2)));
typedef float f32x4 __attribute__((ext_vector_type(4)));
typedef int i32x4 __attribute__((ext_vector_type(4)));

// --- swizzle for 64-half rows (attn K/V tiles) ----------------------------
__device__ __forceinline__ int sw64(int row, int col) {
  return (row << 6) + ((((col >> 3) ^ row) & 7) << 3) + (col & 7);
}

// --- packed-tile swizzle for T x 32-half tiles (proj A/W tiles) -----------
__device__ __forceinline__ int toff(int r, int k) {
  const int rp = r >> 1;
  const int g = (((r & 1) << 2) + (k >> 3)) ^ (rp & 7);
  return (rp << 6) + ((g & 7) << 3) + (k & 7);
}

// async global->LDS, 16 B per lane; LDS dest wave-uniform, lanes +16 B
__device__ __forceinline__ void gld16(const _Float16* g, _Float16* l) {
  __builtin_amdgcn_global_load_lds(
      (const __attribute__((address_space(1))) void*)g,
      (__attribute__((address_space(3))) void*)l, 16, 0, 0);
}

__device__ __forceinline__ float fexp2(float x) {
  return __builtin_amdgcn_exp2f(x);
}

// pack two f32 -> one u32 of 2x f16 (RNE, same rounding as scalar casts)
__device__ __forceinline__ unsigned pack_h2(float a, float b) {
  union { half2_t h; unsigned u; } cv;
  cv.h[0] = (_Float16)a;
  cv.h[1] = (_Float16)b;
  return cv.u;
}

// in-place cross-lane swaps (gfx950): both operands exchanged
__device__ __forceinline__ void plswap16(unsigned& a, unsigned& b) {
  asm("v_permlane16_swap_b32 %0, %1" : "+v"(a), "+v"(b));
}
__device__ __forceinline__ void plswap32(unsigned& a, unsigned& b) {
  asm("v_permlane32_swap_b32 %0, %1" : "+v"(a), "+v"(b));
}

// ===========================================================================
// prep: (a) W fp32 [k][n] -> fp16 pre-swizzled 96x32 tile blocks (transposed)
//       (b) zero q16 pad region d in [32,64) only (proj writes d<36 after)
//       (c) ones into vblk row d=36 of every tile (PV MFMA then yields the
//           softmax denominator in oacc col 36 for free)
// ===========================================================================
#define WBLK 1296   // 4*288*288 / 256
#define QZBLK 1024  // BHN rows * 4 i32x4 (upper 32 halves) / 256
#define VOBLK 256   // BH*32*64 / 256

__global__ __launch_bounds__(256) void prep_kernel(
    const float* __restrict__ Wq, const float* __restrict__ Wk,
    const float* __restrict__ Wv, const float* __restrict__ Wo,
    _Float16* __restrict__ wblk, _Float16* __restrict__ q16,
    _Float16* __restrict__ vblk) {
  const int bid = blockIdx.x;
  const int tid = threadIdx.x;
  if (bid < WBLK) {
    const int j = bid * 256 + tid;  // (m, k, n)
    const int m = j / (E * E);
    const int rem = j - m * (E * E);
    const int k = rem / E, n = rem - k * E;
    const float* W = (m == 0) ? Wq : (m == 1) ? Wk : (m == 2) ? Wv : Wo;
    wblk[(size_t)((m * 3 + n / 96) * 9 + (k >> 5)) * 3072 +
         toff(n % 96, k & 31)] = (_Float16)W[(size_t)k * E + n];
  } else if (bid < WBLK + QZBLK) {
    const int j = (bid - WBLK) * 256 + tid;  // (row, sub)
    const int row = j >> 2, sub = j & 3;
    ((i32x4*)q16)[(size_t)row * 8 + 4 + sub] = (i32x4){0, 0, 0, 0};
  } else {
    const int j = (bid - WBLK - QZBLK) * 256 + tid;  // (bh, kt, c)
    const int bh = j >> 11;
    const int rem = j & 2047;
    const int kt = rem >> 6, c = rem & 63;
    vblk[((size_t)bh * 32 + kt) * 3072 + sw64(36, c)] = (_Float16)1.0f;
  }
}

// ===========================================================================
// QKV projection: A read directly from fp32 x (float4, register-prefetched,
// converted during LDS write); W staged via gld16 from pre-swizzled wblk.
// R8->R9: PN 96->48 (W half-panels are contiguous: toff(r+48,k)=toff(r,k)
// +1536) -> grid 64x6x3 = 1152 blocks = 4.5/CU, fixing the 576-block
// (2.25/CU) ceil-load imbalance (3 vs 2 resident blocks per CU).
// ===========================================================================
#define PM 128
#define PN 48

struct QKVArgs {
  const float* x[3];
  const float* bias[3];
  _Float16* out[3];
};

__global__ __launch_bounds__(256, 4) void proj_qkv_kernel(
    QKVArgs A, const _Float16* __restrict__ wblk) {
  __shared__ __align__(16) _Float16 abuf[2][4096];   // 16 KB
  __shared__ __align__(16) _Float16 wbuf[2][1536];   // 6 KB

  const int tid = threadIdx.x;
  const int lane = tid & 63, w = tid >> 6;
  const int quad = lane >> 4, l15 = lane & 15;
  const int mode = blockIdx.z;
  const int RB = blockIdx.x, CT = blockIdx.y;
  const float* __restrict__ x = A.x[mode];
  // 48-col half-panel of the pre-swizzled 96x32 W tile blocks
  const _Float16* __restrict__ wb = wblk +
      (size_t)(mode * 3 + (CT >> 1)) * 9 * 3072 + (CT & 1) * 1536;
  const int row0 = RB * PM;

  float4 apre[4];
  auto loadA = [&](int C) {
#pragma unroll
    for (int iu = 0; iu < 4; ++iu) {
      const int i = tid + 256 * iu, r = i >> 3, c4 = i & 7;
      apre[iu] = *(const float4*)&x[(size_t)(row0 + r) * E + C * 32 + c4 * 4];
    }
  };
  auto writeA = [&](_Float16* dst) {
#pragma unroll
    for (int iu = 0; iu < 4; ++iu) {
      const int i = tid + 256 * iu, r = i >> 3, c4 = i & 7;
      half4_t h = {(_Float16)apre[iu].x, (_Float16)apre[iu].y,
                   (_Float16)apre[iu].z, (_Float16)apre[iu].w};
      *(half4_t*)&dst[toff(r, c4 * 4)] = h;
    }
  };

  f32x4 acc[2][3];
#pragma unroll
  for (int t = 0; t < 2; ++t)
#pragma unroll
    for (int nt = 0; nt < 3; ++nt) acc[t][nt] = (f32x4){0.f, 0.f, 0.f, 0.f};

  // pre-loop: A(0) -> abuf[0]; W(0) gld16; prefetch A(1)
  loadA(0);
  writeA(abuf[0]);
  for (int seg = w; seg < 3; seg += 4)
    gld16(wb + seg * 512 + lane * 8, wbuf[0] + seg * 512);
  loadA(1);

  for (int C = 0; C < 9; ++C) {
    const int cur = C & 1;
    __syncthreads();  // drains abuf[cur] writes + wbuf[cur] gld16
    if (C + 1 < 9) {
      for (int seg = w; seg < 3; seg += 4)
        gld16(wb + (C + 1) * 3072 + seg * 512 + lane * 8,
              wbuf[cur ^ 1] + seg * 512);
      writeA(abuf[cur ^ 1]);
      if (C + 2 < 9) loadA(C + 2);
    }
    half8_t ah[2];
#pragma unroll
    for (int t = 0; t < 2; ++t)
      ah[t] = *(const half8_t*)&abuf[cur][toff(w * 32 + t * 16 + l15, quad * 8)];
#pragma unroll
    for (int nt = 0; nt < 3; ++nt) {
      const half8_t bf = *(const half8_t*)&wbuf[cur][toff(nt * 16 + l15, quad * 8)];
#pragma unroll
      for (int t = 0; t < 2; ++t)
        acc[t][nt] = __builtin_amdgcn_mfma_f32_16x16x32_f16(ah[t], bf, acc[t][nt], 0, 0, 0);
    }
  }

  const float* __restrict__ bias = A.bias[mode];
  _Float16* __restrict__ outp = A.out[mode];
  const float scale = (mode == 0) ? 0.24044917348149868f : 1.0f;
  const int col0 = CT * PN;
#pragma unroll
  for (int nt = 0; nt < 3; ++nt) {
    const int col = col0 + nt * 16 + l15;
    const int h = col / 36, d = col - h * 36;
    const float bc = bias[col];
#pragma unroll
    for (int t = 0; t < 2; ++t) {
#pragma unroll
      for (int r = 0; r < 4; ++r) {
        const int row = row0 + w * 32 + t * 16 + quad * 4 + r;
        const int b = row >> 11, n = row & (NSEQ - 1);
        const int bh = b * NH + h;
        const _Float16 val = (_Float16)((acc[t][nt][r] + bc) * scale);
        if (mode == 0) {
          outp[((size_t)bh * NSEQ + n) * 64 + d] = val;
        } else {
          const int kt = n >> 6, c = n & 63;
          if (mode == 1) {
            outp[((size_t)bh * 32 + kt) * 4096 + sw64(c, d)] = val;
          } else {
            const int pc = ((c & 15) << 2) | (c >> 4);
            outp[((size_t)bh * 32 + kt) * 3072 + sw64(d, pc)] = val;
          }
        }
      }
    }
  }
}

// ===========================================================================
// fp16 MFMA flash attention (R4 core, best measured). Epilogue writes pacc16
// row-major [chunk][row 8192][E 288] + psum_r[chunk][row][h] for fused
// combine in proj_o.
// ===========================================================================
#define QB 128
#define KT 64
#define SPLIT 2
#define NIT (32 / SPLIT)  // K-tiles per block

__device__ __forceinline__ void stage_tile(const _Float16* kg, const _Float16* vg,
                                           _Float16* kb, _Float16* vb, int w,
                                           int lane) {
#pragma unroll
  for (int seg = w; seg < 8; seg += 4)
    gld16(kg + seg * 512 + lane * 8, kb + seg * 512);
  for (int seg = w; seg < 6; seg += 4)
    gld16(vg + seg * 512 + lane * 8, vb + seg * 512);
}

__global__ __launch_bounds__(256, 4) void attn_kernel(
    const _Float16* __restrict__ q16, const _Float16* __restrict__ kblk,
    const _Float16* __restrict__ vblk, _Float16* __restrict__ pacc16,
    float* __restrict__ psum_r) {
  __shared__ __align__(16) _Float16 kbuf[2][KT * 64];  // 16 KB
  __shared__ __align__(16) _Float16 vbuf[2][48 * 64];  // 12 KB

  const int tid = threadIdx.x;
  const int lane = tid & 63;
  const int w = tid >> 6;
  const int quad = lane >> 4;
  const int l15 = lane & 15;

  const int id = blockIdx.x;
  const int xcd = id & 7;
  const int qb = (id >> 3) & 15;
  const int g = id >> 7;
  const int bhc = g * 8 + xcd;  // [0, BH*SPLIT)
  const int bh = bhc >> 1;
  const int chunk = bhc & 1;
  const int q0 = qb * QB;

  const _Float16* qbase = q16 + ((size_t)bh * NSEQ + q0 + w * 32) * 64;
  half8_t qf[2][2];
#pragma unroll
  for (int t = 0; t < 2; ++t)
#pragma unroll
    for (int kc = 0; kc < 2; ++kc)
      qf[t][kc] = *(const half8_t*)&qbase[(t * 16 + l15) * 64 + kc * 32 + quad * 8];

  f32x4 oacc[2][3];
#pragma unroll
  for (int t = 0; t < 2; ++t)
#pragma unroll
    for (int nt = 0; nt < 3; ++nt) oacc[t][nt] = (f32x4){0.f, 0.f, 0.f, 0.f};

  const f32x4 zf = (f32x4){0.f, 0.f, 0.f, 0.f};

  const int t0 = chunk * NIT;
  const _Float16* kbase = kblk + ((size_t)bh * 32 + t0) * 4096;
  const _Float16* vbase = vblk + ((size_t)bh * 32 + t0) * 3072;

  stage_tile(kbase, vbase, kbuf[0], vbuf[0], w, lane);

  for (int it = 0; it < NIT; ++it) {
    const int cur = it & 1;
    __syncthreads();
    if (it + 1 < NIT)
      stage_tile(kbase + (it + 1) * 4096, vbase + (it + 1) * 3072,
                 kbuf[cur ^ 1], vbuf[cur ^ 1], w, lane);

    // hoist V fragments (shared across both stripes; row 36 = ones)
    half8_t vf[2][3];
#pragma unroll
    for (int kc = 0; kc < 2; ++kc)
#pragma unroll
      for (int nt = 0; nt < 3; ++nt)
        vf[kc][nt] = *(const half8_t*)&vbuf[cur][sw64(nt * 16 + l15, kc * 32 + quad * 8)];

    // ---- QK^T (swapped: D = K.Q^T, lane holds q-row l15) + exp + pack ----
    unsigned pk[2][4][2];
#pragma unroll
    for (int a = 0; a < 2; ++a) {  // s-pair (2a, 2a+1)
      f32x4 sc[2][2];              // [stripe][s within pair]
      __builtin_amdgcn_s_setprio(1);
#pragma unroll
      for (int sp = 0; sp < 2; ++sp) {
        const int s = a * 2 + sp;
        const half8_t kf0 = *(const half8_t*)&kbuf[cur][sw64(s * 16 + l15, quad * 8)];
        const half8_t kf1 = *(const half8_t*)&kbuf[cur][sw64(s * 16 + l15, 32 + quad * 8)];
#pragma unroll
        for (int t = 0; t < 2; ++t) {
          f32x4 c0 = __builtin_amdgcn_mfma_f32_16x16x32_f16(
              kf0, qf[t][0], zf, 0, 0, 0);
          sc[t][sp] = __builtin_amdgcn_mfma_f32_16x16x32_f16(
              kf1, qf[t][1], c0, 0, 0, 0);
        }
      }
      __builtin_amdgcn_s_setprio(0);
#pragma unroll
      for (int t = 0; t < 2; ++t)
#pragma unroll
        for (int r = 0; r < 4; ++r) {
          const float p0 = fexp2(sc[t][0][r]);
          const float p1 = fexp2(sc[t][1][r]);
          pk[t][r][a] = pack_h2(p0, p1);
        }
    }

    // ---- in-register transpose: pk -> PV A-fragments (both kc at once) ----
    half8_t pa[2][2];
#pragma unroll
    for (int t = 0; t < 2; ++t) {
      union { unsigned u[4]; half8_t h; } f0, f1;
#pragma unroll
      for (int v = 0; v < 4; ++v) {
        unsigned x = pk[t][v >> 1][v & 1];
        unsigned y = pk[t][(v >> 1) + 2][v & 1];
        plswap16(x, y);
        plswap32(x, y);
        f0.u[v] = x;
        f1.u[v] = y;
      }
      pa[t][0] = f0.h;
      pa[t][1] = f1.h;
    }

    // ---- PV: V fragments read once, shared across both stripes ----
    __builtin_amdgcn_s_setprio(1);
#pragma unroll
    for (int kc = 0; kc < 2; ++kc)
#pragma unroll
      for (int nt = 0; nt < 3; ++nt) {
#pragma unroll
        for (int t = 0; t < 2; ++t)
          oacc[t][nt] = __builtin_amdgcn_mfma_f32_16x16x32_f16(pa[t][kc], vf[kc][nt], oacc[t][nt], 0, 0, 0);
      }
    __builtin_amdgcn_s_setprio(0);
  }

  const int b = bh >> 3, h = bh & 7;
#pragma unroll
  for (int t = 0; t < 2; ++t) {
#pragma unroll
    for (int r = 0; r < 4; ++r) {
      const int n = q0 + w * 32 + t * 16 + quad * 4 + r;
      const size_t rowg = (size_t)b * NSEQ + n;
      const size_t base = ((size_t)chunk * ROWS + rowg) * E + h * 36;
      // col 36 of oacc (nt=2, l15==4) = sum over this chunk's kv of P (f16)
      if (l15 == 4) psum_r[((size_t)chunk * ROWS + rowg) * 8 + h] = oacc[t][2][r];
#pragma unroll
      for (int nt = 0; nt < 3; ++nt) {
        const int col = nt * 16 + l15;
        if (col < HD) pacc16[base + col] = (_Float16)oacc[t][nt][r];
      }
    }
  }
}

// ===========================================================================
// O projection with FUSED split-K combine (unchanged from R7).
// PM=64 x PN=48 -> grid (128, 6) = 768 blocks = 3/CU. fp32 out.
// ===========================================================================
__global__ __launch_bounds__(256, 4) void proj_o_kernel(
    const _Float16* __restrict__ pacc16, const float* __restrict__ psum_r,
    const _Float16* __restrict__ wblk_o, const float* __restrict__ bias,
    float* __restrict__ out) {
  __shared__ __align__(16) _Float16 hbuf[2][2048];  // 8 KB
  __shared__ __align__(16) _Float16 lbuf[2][2048];  // 8 KB
  __shared__ __align__(16) _Float16 wbuf[2][1536];  // 6 KB
  __shared__ float invt[512];                       // [row 64][h 8], 2 KB

  const int tid = threadIdx.x;
  const int lane = tid & 63, w = tid >> 6;
  const int quad = lane >> 4, l15 = lane & 15;
  const int RB = blockIdx.x, CT = blockIdx.y;
  const int row0 = RB * 64;
  // 48-col half-panel of the pre-swizzled 96x32 W tiles:
  // toff(r+48,k) == toff(r,k)+1536, so half-panels are contiguous.
  const _Float16* __restrict__ wb =
      wblk_o + (size_t)(CT >> 1) * 9 * 3072 + (CT & 1) * 1536;

  // ---- build inv table: inv[r][h] = 1/(psum0 + psum1) ----
#pragma unroll
  for (int u = 0; u < 2; ++u) {
    const int idx = tid + u * 256;  // r*8 + h
    const int r = idx >> 3, hh = idx & 7;
    const float s = psum_r[(size_t)(row0 + r) * 8 + hh] +
                    psum_r[((size_t)ROWS + row0 + r) * 8 + hh];
    invt[idx] = 1.0f / s;
  }

  // ---- A prefetch (thread -> row=tid>>2, 8 cols at (tid&3)*8) ----
  const int arow = tid >> 2;
  const int acol8 = (tid & 3) * 8;
  half8_t ap0, ap1;
  auto loadA = [&](int C) {
    const size_t off = (size_t)(row0 + arow) * E + C * 32 + acol8;
    ap0 = *(const half8_t*)&pacc16[off];
    ap1 = *(const half8_t*)&pacc16[(size_t)ROWS * E + off];
  };
  auto writeA = [&](int C, _Float16* hd, _Float16* ld) {
    const int colb = C * 32 + acol8;
    const int h0 = colb / 36;
    const int h1 = (colb + 7) / 36;
    const float i0 = invt[(arow << 3) + h0];
    const float i1 = invt[(arow << 3) + h1];
    const int split = h1 * 36 - colb;  // j < split -> h0 (h0==h1 -> split<=0 -> all i1)
    half8_t hv, lv;
#pragma unroll
    for (int j = 0; j < 8; ++j) {
      const float inv = (j < split) ? i0 : i1;
      const float a = (float)ap0[j] + (float)ap1[j];
      const float val = a * inv;
      const _Float16 hi = (_Float16)val;
      hv[j] = hi;
      lv[j] = (_Float16)(val - (float)hi);
    }
    *(half8_t*)&hd[toff(arow, acol8)] = hv;
    *(half8_t*)&ld[toff(arow, acol8)] = lv;
  };

  f32x4 acc[3];
#pragma unroll
  for (int nt = 0; nt < 3; ++nt) acc[nt] = (f32x4){0.f, 0.f, 0.f, 0.f};

  loadA(0);
  __syncthreads();  // invt ready before writeA(0) reads it
  writeA(0, hbuf[0], lbuf[0]);
  for (int seg = w; seg < 3; seg += 4)
    gld16(wb + seg * 512 + lane * 8, wbuf[0] + seg * 512);
  loadA(1);

  for (int C = 0; C < 9; ++C) {
    const int cur = C & 1;
    __syncthreads();  // drains wbuf gld16 + hbuf/lbuf ds_writes for chunk C
    if (C + 1 < 9) {
      for (int seg = w; seg < 3; seg += 4)
        gld16(wb + (C + 1) * 3072 + seg * 512 + lane * 8,
              wbuf[cur ^ 1] + seg * 512);
      writeA(C + 1, hbuf[cur ^ 1], lbuf[cur ^ 1]);
      if (C + 2 < 9) loadA(C + 2);
    }
    const half8_t ah = *(const half8_t*)&hbuf[cur][toff(w * 16 + l15, quad * 8)];
    const half8_t al = *(const half8_t*)&lbuf[cur][toff(w * 16 + l15, quad * 8)];
#pragma unroll
    for (int nt = 0; nt < 3; ++nt) {
      const half8_t bf = *(const half8_t*)&wbuf[cur][toff(nt * 16 + l15, quad * 8)];
      acc[nt] = __builtin_amdgcn_mfma_f32_16x16x32_f16(ah, bf, acc[nt], 0, 0, 0);
      acc[nt] = __builtin_amdgcn_mfma_f32_16x16x32_f16(al, bf, acc[nt], 0, 0, 0);
    }
  }

#pragma unroll
  for (int nt = 0; nt < 3; ++nt) {
    const int col = CT * 48 + nt * 16 + l15;
    const float bc = bias[col];
#pragma unroll
    for (int r = 0; r < 4; ++r) {
      const int row = row0 + w * 16 + quad * 4 + r;
      out[(size_t)row * E + col] = acc[nt][r] + bc;
    }
  }
}

// ===========================================================================
extern "C" void kernel_launch(void* const* d_in, const int* in_sizes, int n_in,
                              void* d_out, int out_size, void* d_ws,
                              size_t ws_size, hipStream_t stream) {
  const float* query = (const float*)d_in[0];
  const float* key_ = (const float*)d_in[1];
  const float* value = (const float*)d_in[2];
  const float* Wq = (const float*)d_in[3];
  const float* bq = (const float*)d_in[4];
  const float* Wk = (const float*)d_in[5];
  const float* bk = (const float*)d_in[6];
  const float* Wv = (const float*)d_in[7];
  const float* bv = (const float*)d_in[8];
  const float* Wo = (const float*)d_in[9];
  const float* bo = (const float*)d_in[10];
  float* out = (float*)d_out;

  // workspace layout
  _Float16* q16 = (_Float16*)d_ws;                    // BH*NSEQ*64
  _Float16* kblk = q16 + (size_t)BH * NSEQ * 64;      // BH*32*4096
  _Float16* vblk = kblk + (size_t)BH * 32 * 4096;     // BH*32*3072
  _Float16* wblk = vblk + (size_t)BH * 32 * 3072;     // 4*3*9*3072
  _Float16* pacc16 = wblk + (size_t)4 * 3 * 9 * 3072; // SPLIT*ROWS*E
  float* psum_r = (float*)(pacc16 + (size_t)SPLIT * ROWS * E);  // SPLIT*ROWS*8

  prep_kernel<<<WBLK + QZBLK + VOBLK, 256, 0, stream>>>(Wq, Wk, Wv, Wo, wblk,
                                                        q16, vblk);

  QKVArgs qa;
  qa.x[0] = query; qa.x[1] = key_; qa.x[2] = value;
  qa.bias[0] = bq; qa.bias[1] = bk; qa.bias[2] = bv;
  qa.out[0] = q16; qa.out[1] = kblk; qa.out[2] = vblk;
  proj_qkv_kernel<<<dim3(ROWS / PM, E / PN, 3), 256, 0, stream>>>(qa, wblk);

  attn_kernel<<<dim3((NSEQ / QB) * BH * SPLIT), 256, 0, stream>>>(
      q16, kblk, vblk, pacc16, psum_r);

  proj_o_kernel<<<dim3(ROWS / 64, E / 48), 256, 0, stream>>>(
      pacc16, psum_r, wblk + (size_t)3 * 3 * 9 * 3072, bo, out);
}